// Round 3
// baseline (10190.285 us; speedup 1.0000x reference)
//
#include <hip/hip_runtime.h>

// WeatherLSTM: B=256, T=128, I=64, H=2048, O=24
// g = [h|x] @ Wcat + b ; i,f,o,c gates ; 151 sequential steps.
// R3: PERSISTENT kernel, 256 blocks = 1/CU. Each block pins its 32-col Wh
// slice (128 KB) in LDS for all steps; only activations stream from L2.
// Grid barrier between steps via agent-scope atomics.

#define NB 256
#define NH 2048
#define NI 64
#define NK 2112      // NH + NI
#define NPK 8192     // 4*NH
#define NSTEPS 151   // 128 encoder + 23 decoder
#define NO 24

typedef __bf16 bf16x8 __attribute__((ext_vector_type(8)));
typedef short short8 __attribute__((ext_vector_type(8)));
typedef float f32x4 __attribute__((ext_vector_type(4)));
typedef unsigned short u16;

__device__ __forceinline__ u16 f2bf(float f) {
  union { float f; unsigned u; } v; v.f = f;
  unsigned r = v.u + 0x7FFFu + ((v.u >> 16) & 1u);  // RNE
  return (u16)(r >> 16);
}

__device__ __forceinline__ void gload16(const void* g, void* l) {
  __builtin_amdgcn_global_load_lds(
      (const __attribute__((address_space(1))) unsigned int*)g,
      (__attribute__((address_space(3))) unsigned int*)l, 16, 0, 0);
}

__device__ __forceinline__ float sigmoidf_(float x) {
  return 1.f / (1.f + __expf(-x));
}
__device__ __forceinline__ float tanhf_(float x) {
  x = fminf(15.f, fmaxf(-15.f, x));
  float e = __expf(2.f * x);
  return (e - 1.f) / (e + 1.f);
}

// ---- pack [Wh;Wx] fp32 [k][4H] -> Wp bf16 [p][k], p = u*4+g, via LDS transpose tile
__global__ __launch_bounds__(256) void wl_pack_w(const float* __restrict__ Wx,
                                                 const float* __restrict__ Wh,
                                                 u16* __restrict__ Wp) {
  __shared__ float s[64][65];
  const int j0 = blockIdx.x * 64, k0 = blockIdx.y * 64;
  const int tid = threadIdx.x;
  const int jl = tid & 63, kg = tid >> 6;  // kg in 0..3
#pragma unroll
  for (int it = 0; it < 16; ++it) {
    int kl = it * 4 + kg;
    int k = k0 + kl, j = j0 + jl;
    float v = (k < NH) ? Wh[(size_t)k * NPK + j] : Wx[(size_t)(k - NH) * NPK + j];
    s[kl][jl] = v;
  }
  __syncthreads();
  int j = j0 + jl;
  int p = (j & (NH - 1)) * 4 + (j >> 11);  // u*4 + gate
  short8 v0, v1;
#pragma unroll
  for (int e = 0; e < 8; ++e) {
    v0[e] = (short)f2bf(s[kg * 16 + e][jl]);
    v1[e] = (short)f2bf(s[kg * 16 + 8 + e][jl]);
  }
  short8* dst = (short8*)(Wp + (size_t)p * NK + k0 + kg * 16);
  dst[0] = v0;
  dst[1] = v1;
}

// ---- bsum[p] = bx[j] + bh[j]
__global__ __launch_bounds__(256) void wl_bsum(const float* __restrict__ bx,
                                               const float* __restrict__ bh,
                                               float* __restrict__ bsum) {
  int p = blockIdx.x * 256 + threadIdx.x;
  int j = (p & 3) * NH + (p >> 2);
  bsum[p] = bx[j] + bh[j];
}

// ---- xall[t][b][i] bf16: encoder = trains, decoder = dec*Win + b_in
__global__ __launch_bounds__(256) void wl_xall(const float* __restrict__ trains,
                                               const float* __restrict__ dec,
                                               const float* __restrict__ Win,
                                               const float* __restrict__ b_in,
                                               u16* __restrict__ xall) {
  int idx = blockIdx.x * 256 + threadIdx.x;
  int i = idx & 63;
  int b = (idx >> 6) & 255;
  int t = idx >> 14;
  float v;
  if (t < 128)
    v = trains[((size_t)b * 128 + t) * 64 + i];
  else
    v = dec[b * 23 + (t - 128)] * Win[i] + b_in[i];
  xall[idx] = f2bf(v);
}

// ---- persistent: all 151 steps. 256 blocks x 256 threads, 1 block/CU.
// LDS: Wh slice [32 cols][2048 k] bf16 swizzled (131072 B) + A dbuf 2x16KB.
// Per step: 64 k-tiles (BK=32) from hin + 2 k-tiles from xall; B for the x
// part read per-lane from global Wp (L2-resident, 4KB/block).
__global__ __launch_bounds__(256, 1) void wl_persist(const u16* __restrict__ Wpg,
                                                     const float* __restrict__ bsum,
                                                     const u16* __restrict__ xall,
                                                     u16* __restrict__ hcat,  // 2 bufs
                                                     float* __restrict__ c_t, // [unit][b]
                                                     float* __restrict__ ypart,
                                                     const float* __restrict__ Wout,
                                                     unsigned* __restrict__ bar) {
  __shared__ char lds[163840];  // Wh 131072 | A0 16384 | A1 16384 (A region = gtile in epilogue)
  char* const abuf = lds + 131072;

  const int cg = blockIdx.x;        // col-group 0..255
  const int p0 = cg * 32, u0 = cg * 8;
  const int tid = threadIdx.x;
  const int wv = tid >> 6, lane = tid & 63;
  const int l15 = lane & 15, lhi = lane >> 4;
  // A staging decomposition: 1KB chunk = 16 rows x 64B; lane -> (srow16, sc4)
  const int srow16 = lane >> 2, sc4 = lane & 3;
  const int kchunk = sc4 ^ ((srow16 >> 1) & 3);      // pre-swizzled source chunk
  const int afr_swz = (lhi ^ ((l15 >> 1) & 3)) << 4; // A fragment read swizzle

  // ---- one-time: stage Wh slice into LDS (swizzled for 2-way-max bfr reads)
  for (int i = 0; i < 32; ++i) {
    int idx = i * 256 + tid;
    int col = idx >> 8, ch = idx & 255;  // col 0..31, 16B chunk 0..255
    bf16x8 v = *(const bf16x8*)(Wpg + (size_t)(p0 + col) * NK + ch * 8);
    *(bf16x8*)(lds + col * 4096 + ((ch ^ (col & 7)) << 4)) = v;
  }
  __syncthreads();

  for (int t = 0; t < NSTEPS; ++t) {
    const u16* __restrict__ hin = hcat + (size_t)(t & 1) * NB * NH;
    u16* __restrict__ hout = hcat + (size_t)((t + 1) & 1) * NB * NH;

    f32x4 acc[4][2] = {};

    auto stage = [&](int kt, int buf) {
      const u16* asrc; int astr;
      if (kt < 64) { asrc = hin + kt * 32;                    astr = NH; }
      else         { asrc = xall + (size_t)t * NB * NI + (kt - 64) * 32; astr = NI; }
#pragma unroll
      for (int i = 0; i < 4; ++i) {
        int qa = wv * 4 + i;              // 1KB chunk 0..15
        int row = qa * 16 + srow16;       // batch row 0..255
        gload16(asrc + (size_t)row * astr + kchunk * 8, abuf + buf * 16384 + qa * 1024);
      }
    };

    stage(0, 0);
#pragma unroll 2
    for (int kt = 0; kt < 66; ++kt) {
      const int buf = kt & 1;
      if (kt < 65) {
        stage(kt + 1, buf ^ 1);
        asm volatile("s_waitcnt vmcnt(4)" ::: "memory");  // current tile's 4 loads done
      } else {
        asm volatile("s_waitcnt vmcnt(0)" ::: "memory");
      }
      __syncthreads();
      const char* Ab = abuf + buf * 16384;
      bf16x8 bfr[2];
#pragma unroll
      for (int n = 0; n < 2; ++n) {
        int col = n * 16 + l15;
        if (kt < 64)
          bfr[n] = *(const bf16x8*)(lds + col * 4096 + (((kt * 4 + lhi) ^ (col & 7)) << 4));
        else
          bfr[n] = *(const bf16x8*)(Wpg + (size_t)(p0 + col) * NK + 2048 + (kt - 64) * 32 + lhi * 8);
      }
#pragma unroll
      for (int m = 0; m < 4; ++m) {
        int row = wv * 64 + m * 16 + l15;
        bf16x8 afr = *(const bf16x8*)(Ab + row * 64 + afr_swz);
#pragma unroll
        for (int n = 0; n < 2; ++n)
          acc[m][n] = __builtin_amdgcn_mfma_f32_16x16x32_bf16(afr, bfr[n], acc[m][n], 0, 0, 0);
      }
      __syncthreads();
    }

    // ---- epilogue: acc -> gtile (aliases A dbuf region, swizzled), then gates.
    // C/D layout: col = n*16 + l15, rows = wv*64 + m*16 + lhi*4 + r.
    float* gtile = (float*)abuf;  // [col 0..31] x [row 0..255] f32, 16B-chunk XOR swizzle
#pragma unroll
    for (int m = 0; m < 4; ++m)
#pragma unroll
      for (int n = 0; n < 2; ++n) {
        int col = n * 16 + l15;
        int chunk = wv * 16 + m * 4 + lhi;  // row>>2
        *(f32x4*)(abuf + col * 1024 + ((chunk ^ (col & 7)) << 4)) = acc[m][n];
      }
    __syncthreads();

    const int b = tid;
    const bool emit = (t >= 127);
    float yacc = 0.f;
    short8 hv;
#pragma unroll
    for (int u = 0; u < 8; ++u) {
      float g[4];
#pragma unroll
      for (int gi = 0; gi < 4; ++gi) {
        int col = u * 4 + gi;
        g[gi] = *(const float*)(abuf + col * 1024 + (((b >> 2) ^ (col & 7)) << 4) + (b & 3) * 4);
      }
      const float4 bs = *(const float4*)(bsum + p0 + u * 4);
      float si = sigmoidf_(g[0] + bs.x);
      float sf = sigmoidf_(g[1] + bs.y);
      float so = sigmoidf_(g[2] + bs.z);
      float tc = tanhf_(g[3] + bs.w);
      size_t ci = (size_t)(u0 + u) * NB + b;
      float cn = sf * c_t[ci] + si * tc;
      float h = so * tanhf_(cn);
      c_t[ci] = cn;
      hv[u] = (short)f2bf(h);
      if (emit) yacc += h * Wout[u0 + u];
    }
    *(short8*)(hout + (size_t)b * NH + u0) = hv;  // 16B store
    if (emit) ypart[(((size_t)(t - 127)) * 256 + cg) * NB + b] = yacc;

    // ---- grid barrier (device scope: acq_rel add flushes/invalidates L2)
    __syncthreads();
    if (tid == 0) {
      unsigned target = 256u * (t + 1);
      __hip_atomic_fetch_add(bar, 1u, __ATOMIC_ACQ_REL, __HIP_MEMORY_SCOPE_AGENT);
      while (__hip_atomic_load(bar, __ATOMIC_ACQUIRE, __HIP_MEMORY_SCOPE_AGENT) < target)
        __builtin_amdgcn_s_sleep(2);
    }
    __syncthreads();
  }
}

// ---- y[b][j] = bout + sum_cg ypart[j][cg][b]
__global__ __launch_bounds__(256) void wl_finy(const float* __restrict__ ypart,
                                               const float* __restrict__ bout,
                                               float* __restrict__ out) {
  int j = blockIdx.x;
  int b = threadIdx.x;
  const float* yp = ypart + (size_t)j * NB * NB;
  float s = bout[0];
#pragma unroll 8
  for (int i = 0; i < 256; ++i) s += yp[i * 256 + b];
  out[b * NO + j] = s;
}

extern "C" void kernel_launch(void* const* d_in, const int* in_sizes, int n_in,
                              void* d_out, int out_size, void* d_ws, size_t ws_size,
                              hipStream_t stream) {
  const float* trains = (const float*)d_in[0];
  const float* dec    = (const float*)d_in[1];
  const float* Wx     = (const float*)d_in[2];
  const float* bx     = (const float*)d_in[3];
  const float* Wh     = (const float*)d_in[4];
  const float* bh     = (const float*)d_in[5];
  const float* Win    = (const float*)d_in[6];
  const float* b_in   = (const float*)d_in[7];
  const float* Wout   = (const float*)d_in[8];
  const float* bout   = (const float*)d_in[9];
  float* out = (float*)d_out;
  char* ws = (char*)d_ws;

  u16*      Wp    = (u16*)(ws);                  // 34,603,008 B
  float*    bsum  = (float*)(ws + 34603008);     //     32,768 B
  u16*      xall  = (u16*)(ws + 34635776);       //  4,947,968 B
  u16*      hcat  = (u16*)(ws + 39583744);       //  4,194,304 B (double-buffered h)
  float*    c_t   = (float*)(ws + 43778048);     //  2,097,152 B ([unit][b] fp32)
  unsigned* bar   = (unsigned*)(ws + 45875200);  //         64 B
  float*    ypart = (float*)(ws + 45875264);     //  6,029,312 B  total ~51.9 MB

  // zero h (both buffers) + c + barrier counter in one memset
  hipMemsetAsync(ws + 39583744, 0, 4194304 + 2097152 + 64, stream);
  wl_pack_w<<<dim3(128, 33), 256, 0, stream>>>(Wx, Wh, Wp);
  wl_bsum<<<32, 256, 0, stream>>>(bx, bh, bsum);
  wl_xall<<<(NSTEPS * NB * NI) / 256, 256, 0, stream>>>(trains, dec, Win, b_in, xall);
  wl_persist<<<256, 256, 0, stream>>>(Wp, bsum, xall, hcat, c_t, ypart, Wout, bar);
  wl_finy<<<NO, 256, 0, stream>>>(ypart, bout, out);
}

// Round 4
// 9042.150 us; speedup vs baseline: 1.1270x; 1.1270x over previous
//
#include <hip/hip_runtime.h>

// WeatherLSTM: B=256, T=128, I=64, H=2048, O=24
// R4: persistent kernel, targeted coherence. c in VGPRs; canonical h via
// relaxed agent atomics to L3; per-XCD-group local h copy (normal cached) so
// GEMM A-staging hits warm local L2; NO acquire/release fences -> L2 never
// invalidated; Wh k<1536 pinned in LDS (k-major, conflict-free reads).

#define NB 256
#define NH 2048
#define NI 64
#define NK 2112
#define NPK 8192
#define NSTEPS 151
#define NO 24
#define KLDS 1536            // k range of Wh kept in LDS (24 tiles of 64)

typedef __bf16 bf16x8 __attribute__((ext_vector_type(8)));
typedef short short8 __attribute__((ext_vector_type(8)));
typedef float f32x4 __attribute__((ext_vector_type(4)));
typedef float f32x16 __attribute__((ext_vector_type(16)));
typedef unsigned short u16;
typedef unsigned long long u64;

__device__ __forceinline__ u16 f2bf(float f) {
  union { float f; unsigned u; } v; v.f = f;
  unsigned r = v.u + 0x7FFFu + ((v.u >> 16) & 1u);
  return (u16)(r >> 16);
}

// global->LDS DMA, 16B/lane, SC0 (bypass L1, hit L2)
__device__ __forceinline__ void gload16(const void* g, void* l) {
  __builtin_amdgcn_global_load_lds(
      (const __attribute__((address_space(1))) unsigned int*)g,
      (__attribute__((address_space(3))) unsigned int*)l, 16, 0, 1);
}

__device__ __forceinline__ float sigmoidf_(float x) { return 1.f / (1.f + __expf(-x)); }
__device__ __forceinline__ float tanhf_(float x) {
  x = fminf(15.f, fmaxf(-15.f, x));
  float e = __expf(2.f * x);
  return (e - 1.f) / (e + 1.f);
}

// ---- pack [Wh;Wx] fp32 [k][4H] -> Wp bf16 [p][k], p = u*4+g
__global__ __launch_bounds__(256) void wl_pack_w(const float* __restrict__ Wx,
                                                 const float* __restrict__ Wh,
                                                 u16* __restrict__ Wp) {
  __shared__ float s[64][65];
  const int j0 = blockIdx.x * 64, k0 = blockIdx.y * 64;
  const int tid = threadIdx.x;
  const int jl = tid & 63, kg = tid >> 6;
#pragma unroll
  for (int it = 0; it < 16; ++it) {
    int kl = it * 4 + kg;
    int k = k0 + kl, j = j0 + jl;
    float v = (k < NH) ? Wh[(size_t)k * NPK + j] : Wx[(size_t)(k - NH) * NPK + j];
    s[kl][jl] = v;
  }
  __syncthreads();
  int j = j0 + jl;
  int p = (j & (NH - 1)) * 4 + (j >> 11);
  short8 v0, v1;
#pragma unroll
  for (int e = 0; e < 8; ++e) {
    v0[e] = (short)f2bf(s[kg * 16 + e][jl]);
    v1[e] = (short)f2bf(s[kg * 16 + 8 + e][jl]);
  }
  short8* dst = (short8*)(Wp + (size_t)p * NK + k0 + kg * 16);
  dst[0] = v0;
  dst[1] = v1;
}

__global__ __launch_bounds__(256) void wl_bsum(const float* __restrict__ bx,
                                               const float* __restrict__ bh,
                                               float* __restrict__ bsum) {
  int p = blockIdx.x * 256 + threadIdx.x;
  int j = (p & 3) * NH + (p >> 2);
  bsum[p] = bx[j] + bh[j];
}

__global__ __launch_bounds__(256) void wl_xall(const float* __restrict__ trains,
                                               const float* __restrict__ dec,
                                               const float* __restrict__ Win,
                                               const float* __restrict__ b_in,
                                               u16* __restrict__ xall) {
  int idx = blockIdx.x * 256 + threadIdx.x;
  int i = idx & 63;
  int b = (idx >> 6) & 255;
  int t = idx >> 14;
  float v;
  if (t < 128) v = trains[((size_t)b * 128 + t) * 64 + i];
  else         v = dec[b * 23 + (t - 128)] * Win[i] + b_in[i];
  xall[idx] = f2bf(v);
}

// ======== persistent step kernel: 256 blocks x 512 threads (8 waves) ========
#define SB() __syncthreads()
#define W0() asm volatile("s_waitcnt vmcnt(0)" ::: "memory")
#define W4() asm volatile("s_waitcnt vmcnt(4)" ::: "memory")
#define W8() asm volatile("s_waitcnt vmcnt(8)" ::: "memory")

__global__ __launch_bounds__(512, 1) void wl_persist(
    const u16* __restrict__ Wpg, const float* __restrict__ bsum,
    const u16* __restrict__ xall, u16* __restrict__ hcan,  // [2][256][2048]
    u16* __restrict__ hx,                                  // [8][256][2048]
    float* __restrict__ ypart, const float* __restrict__ Wout,
    unsigned* __restrict__ bars) {
  __shared__ char lds_[163840];  // Wh k-major 96KB | A dbuf 2x32KB (buf0 = gtile)
  char* const abuf = lds_ + 98304;

  const int cg = blockIdx.x;
  const int p0 = cg * 32, u0 = cg * 8;
  const int grp = cg & 7;                 // XCD group (round-robin dispatch)
  const int tid = threadIdx.x;
  const int wv = tid >> 6, lane = tid & 63;
  const int l31 = lane & 31, kgrp = lane >> 5;
  unsigned* const barg = bars;
  unsigned* const barl = bars + 16 + grp * 16;

  u16* const hxg = hx + (size_t)grp * NB * NH;

  // ---- one-time: Wh k<KLDS into LDS, k-major [chunk(16B)][col]: conflict-free
#pragma unroll
  for (int i = 0; i < 12; ++i) {
    int idx = i * 512 + tid;              // 6144 chunks
    int col = idx & 31, ch = idx >> 5;    // ch 0..191
    bf16x8 v = *(const bf16x8*)(Wpg + (size_t)(p0 + col) * NK + ch * 8);
    *(bf16x8*)(lds_ + ch * 512 + col * 16) = v;
  }

  float creg[4] = {0.f, 0.f, 0.f, 0.f};   // cell state, 4 units/thread
  const int b = tid & 255, uh = tid >> 8; // epilogue mapping

  for (int t = 0; t < NSTEPS; ++t) {
    const int par = t & 1;
    const u64* __restrict__ hin64 = (const u64*)(hcan + (size_t)par * NB * NH);
    u64* __restrict__ hout64 = (u64*)(hcan + (size_t)(par ^ 1) * NB * NH);

    // ---- ingest: canonical h (L3, coherent) -> local copy hxg (local L2)
    {
      const int r0 = (cg >> 3) * 8;       // this block's 8 rows
#pragma unroll
      for (int i = 0; i < 4; ++i) {
        int c = tid * 4 + i;              // 2048 chunks of 16B
        int rl = c >> 8, coff = c & 255;
        int gi = (r0 + rl) * 512 + coff * 2;
        u64 v0 = __hip_atomic_load(hin64 + gi, __ATOMIC_RELAXED, __HIP_MEMORY_SCOPE_AGENT);
        u64 v1 = __hip_atomic_load(hin64 + gi + 1, __ATOMIC_RELAXED, __HIP_MEMORY_SCOPE_AGENT);
        u64* d = (u64*)(hxg + (size_t)(r0 + rl) * NH + coff * 8);
        d[0] = v0; d[1] = v1;
      }
    }
    SB();                                  // implicit vmcnt(0): stores in L2
    if (tid == 0) {
      __hip_atomic_fetch_add(barl, 1u, __ATOMIC_RELAXED, __HIP_MEMORY_SCOPE_AGENT);
      unsigned tgt = 32u * (t + 1);
      while (__hip_atomic_load(barl, __ATOMIC_RELAXED, __HIP_MEMORY_SCOPE_AGENT) < tgt)
        __builtin_amdgcn_s_sleep(2);
    }
    SB();

    // ---- GEMM: g[256 rows][32 cols] = [h|x] @ Wp-slice
    f32x16 acc = {};
    bf16x8 bgA[4], bgB[4];

    auto stage = [&](int kt, int buf) {
      const char* a8; size_t astrB;
      if (kt < 32) { a8 = (const char*)(hxg + kt * 64);                 astrB = NH * 2; }
      else         { a8 = (const char*)(xall + (size_t)t * NB * NI);    astrB = NI * 2; }
#pragma unroll
      for (int i = 0; i < 4; ++i) {
        int qa = wv * 4 + i;
        int row = qa * 8 + (lane >> 3);
        int sch = (lane & 7) ^ (lane >> 3);
        gload16(a8 + (size_t)row * astrB + sch * 16, abuf + buf * 32768 + qa * 1024);
      }
    };

#define BGL(T, DST)                                                          \
  {                                                                          \
    _Pragma("unroll") for (int kk = 0; kk < 4; ++kk)                         \
        DST[kk] = *(const bf16x8*)(Wpg + (size_t)(p0 + l31) * NK +           \
                                   (T) * 64 + kk * 16 + kgrp * 8);           \
  }

#define COMPL(T)                                                             \
  {                                                                          \
    const char* Ab = abuf + ((T) & 1) * 32768;                               \
    _Pragma("unroll") for (int kk = 0; kk < 4; ++kk) {                       \
      bf16x8 bfr = *(const bf16x8*)(lds_ + ((T) * 8 + kk * 2 + kgrp) * 512 + \
                                    l31 * 16);                               \
      int crow = wv * 32 + l31;                                              \
      bf16x8 afr = *(const bf16x8*)(Ab + crow * 128 +                        \
                                    (((kk * 2 + kgrp) ^ (crow & 7)) << 4));  \
      acc = __builtin_amdgcn_mfma_f32_32x32x16_bf16(afr, bfr, acc, 0, 0, 0); \
    }                                                                        \
  }

#define COMPG(T, CURB)                                                       \
  {                                                                          \
    const char* Ab = abuf + ((T) & 1) * 32768;                               \
    _Pragma("unroll") for (int kk = 0; kk < 4; ++kk) {                       \
      int crow = wv * 32 + l31;                                              \
      bf16x8 afr = *(const bf16x8*)(Ab + crow * 128 +                        \
                                    (((kk * 2 + kgrp) ^ (crow & 7)) << 4));  \
      acc = __builtin_amdgcn_mfma_f32_32x32x16_bf16(afr, CURB[kk], acc, 0, 0, 0); \
    }                                                                        \
  }

    stage(0, 0);
    for (int kt = 0; kt < 23; ++kt) {      // B from LDS
      SB();
      stage(kt + 1, (kt + 1) & 1);
      W4();
      COMPL(kt);
    }
    // kt = 23: last LDS-B tile; prefetch first global-B tile
    SB(); BGL(24, bgA); stage(24, 0); W8(); COMPL(23);
#pragma unroll 1
    for (int kt = 24; kt < 32; kt += 2) {  // B from global (L2-warm)
      SB(); BGL(kt + 1, bgB); stage(kt + 1, (kt + 1) & 1); W8(); COMPG(kt, bgA);
      SB(); BGL(kt + 2, bgA); stage(kt + 2, (kt + 2) & 1); W8(); COMPG(kt + 1, bgB);
    }
    SB(); W0(); COMPG(32, bgA);            // x tile

    // ---- spill acc -> gtile (= buf0 region), swizzled; barrier first
    SB();
    {
      char* gt = abuf;                     // [32 cols][1KB rows] f32
#pragma unroll
      for (int q = 0; q < 4; ++q) {
        f32x4 v = {acc[q * 4 + 0], acc[q * 4 + 1], acc[q * 4 + 2], acc[q * 4 + 3]};
        int ch = wv * 8 + q * 2 + kgrp;    // row>>2
        *(f32x4*)(gt + l31 * 1024 + ((ch ^ (l31 & 7)) << 4)) = v;
      }
    }
    SB();

    // ---- gates + state update: thread -> (batch b, unit-half uh)
    {
      const bool emit = (t >= 127);
      float yacc = 0.f;
      union { u16 a[4]; u64 v; } hu;
#pragma unroll
      for (int j = 0; j < 4; ++j) {
        int ul = uh * 4 + j;               // local unit 0..7
        float g[4];
#pragma unroll
        for (int gi = 0; gi < 4; ++gi) {
          int col = ul * 4 + gi;
          g[gi] = *(const float*)(abuf + col * 1024 +
                                  ((((b >> 2) ^ (col & 7))) << 4) + (b & 3) * 4);
        }
        const float4 bs = *(const float4*)(bsum + p0 + ul * 4);
        float si = sigmoidf_(g[0] + bs.x);
        float sf = sigmoidf_(g[1] + bs.y);
        float so = sigmoidf_(g[2] + bs.z);
        float tc = tanhf_(g[3] + bs.w);
        float cn = sf * creg[j] + si * tc;
        float h = so * tanhf_(cn);
        creg[j] = cn;
        hu.a[j] = f2bf(h);
        if (emit) yacc += h * Wout[u0 + ul];
      }
      __hip_atomic_store(hout64 + (size_t)b * 512 + cg * 2 + uh, hu.v,
                         __ATOMIC_RELAXED, __HIP_MEMORY_SCOPE_AGENT);
      if (emit) ypart[(((size_t)(t - 127) * 256 + cg) * 2 + uh) * NB + b] = yacc;
    }

    // ---- global barrier (relaxed; __syncthreads drains stores first)
    SB();
    if (tid == 0) {
      __hip_atomic_fetch_add(barg, 1u, __ATOMIC_RELAXED, __HIP_MEMORY_SCOPE_AGENT);
      unsigned tgt = 256u * (t + 1);
      while (__hip_atomic_load(barg, __ATOMIC_RELAXED, __HIP_MEMORY_SCOPE_AGENT) < tgt)
        __builtin_amdgcn_s_sleep(2);
    }
    SB();
  }
#undef BGL
#undef COMPL
#undef COMPG
}

// ---- y[b][j] = bout + sum over 512 partials
__global__ __launch_bounds__(256) void wl_finy(const float* __restrict__ ypart,
                                               const float* __restrict__ bout,
                                               float* __restrict__ out) {
  int j = blockIdx.x;
  int b = threadIdx.x;
  const float* yp = ypart + (size_t)j * 512 * NB;
  float s = bout[0];
#pragma unroll 8
  for (int i = 0; i < 512; ++i) s += yp[i * NB + b];
  out[b * NO + j] = s;
}

extern "C" void kernel_launch(void* const* d_in, const int* in_sizes, int n_in,
                              void* d_out, int out_size, void* d_ws, size_t ws_size,
                              hipStream_t stream) {
  const float* trains = (const float*)d_in[0];
  const float* dec    = (const float*)d_in[1];
  const float* Wx     = (const float*)d_in[2];
  const float* bx     = (const float*)d_in[3];
  const float* Wh     = (const float*)d_in[4];
  const float* bh     = (const float*)d_in[5];
  const float* Win    = (const float*)d_in[6];
  const float* b_in   = (const float*)d_in[7];
  const float* Wout   = (const float*)d_in[8];
  const float* bout   = (const float*)d_in[9];
  float* out = (float*)d_out;
  char* ws = (char*)d_ws;

  u16*      Wp    = (u16*)(ws);                  // 34,603,008
  float*    bsum  = (float*)(ws + 34603008);     // 32,768
  u16*      xall  = (u16*)(ws + 34635776);       // 4,947,968  -> 39,583,744
  u16*      hcan  = (u16*)(ws + 39583744);       // 2,097,152  -> 41,680,896
  u16*      hx    = (u16*)(ws + 41680896);       // 8,388,608  -> 50,069,504
  float*    ypart = (float*)(ws + 50069504);     // 12,582,912 -> 62,652,416
  unsigned* bars  = (unsigned*)(ws + 62652416);  // 4,096      -> 62,656,512

  hipMemsetAsync(ws + 39583744, 0, 1048576, stream);   // hcan[0] = h0 = 0
  hipMemsetAsync(ws + 62652416, 0, 4096, stream);      // barriers
  wl_pack_w<<<dim3(128, 33), 256, 0, stream>>>(Wx, Wh, Wp);
  wl_bsum<<<32, 256, 0, stream>>>(bx, bh, bsum);
  wl_xall<<<(NSTEPS * NB * NI) / 256, 256, 0, stream>>>(trains, dec, Win, b_in, xall);
  wl_persist<<<256, 512, 0, stream>>>(Wp, bsum, xall, hcan, hx, ypart, Wout, bars);
  wl_finy<<<NO, 256, 0, stream>>>(ypart, bout, out);
}

// Round 5
// 3093.762 us; speedup vs baseline: 3.2938x; 2.9227x over previous
//
#include <hip/hip_runtime.h>

// WeatherLSTM: B=256, T=128, I=64, H=2048, O=24
// R5: per-step kernels. Tile 128 rows x 64 packed cols (128 slices x 2 halves,
// XCD-paired). Wp read exactly once/step from L3. Triple-buffered LDS with RAW
// s_barrier + counted vmcnt (no compiler vmcnt(0) drain) -> depth-3 prefetch.

#define NB 256
#define NH 2048
#define NI 64
#define NK 2112
#define NPK 8192
#define NSTEPS 151
#define NO 24

typedef __bf16 bf16x8 __attribute__((ext_vector_type(8)));
typedef short short8 __attribute__((ext_vector_type(8)));
typedef float f32x4 __attribute__((ext_vector_type(4)));
typedef unsigned short u16;

__device__ __forceinline__ u16 f2bf(float f) {
  union { float f; unsigned u; } v; v.f = f;
  unsigned r = v.u + 0x7FFFu + ((v.u >> 16) & 1u);  // RNE
  return (u16)(r >> 16);
}

__device__ __forceinline__ void gload16(const void* g, void* l) {
  __builtin_amdgcn_global_load_lds(
      (const __attribute__((address_space(1))) unsigned int*)g,
      (__attribute__((address_space(3))) unsigned int*)l, 16, 0, 0);
}

__device__ __forceinline__ float sigmoidf_(float x) { return 1.f / (1.f + __expf(-x)); }
__device__ __forceinline__ float tanhf_(float x) {
  x = fminf(15.f, fmaxf(-15.f, x));
  float e = __expf(2.f * x);
  return (e - 1.f) / (e + 1.f);
}

// ---- pack [Wh;Wx] fp32 [k][4H] -> Wp bf16 [p][k], p = u*4+g
__global__ __launch_bounds__(256) void wl_pack_w(const float* __restrict__ Wx,
                                                 const float* __restrict__ Wh,
                                                 u16* __restrict__ Wp) {
  __shared__ float s[64][65];
  const int j0 = blockIdx.x * 64, k0 = blockIdx.y * 64;
  const int tid = threadIdx.x;
  const int jl = tid & 63, kg = tid >> 6;
#pragma unroll
  for (int it = 0; it < 16; ++it) {
    int kl = it * 4 + kg;
    int k = k0 + kl, j = j0 + jl;
    float v = (k < NH) ? Wh[(size_t)k * NPK + j] : Wx[(size_t)(k - NH) * NPK + j];
    s[kl][jl] = v;
  }
  __syncthreads();
  int j = j0 + jl;
  int p = (j & (NH - 1)) * 4 + (j >> 11);
  short8 v0, v1;
#pragma unroll
  for (int e = 0; e < 8; ++e) {
    v0[e] = (short)f2bf(s[kg * 16 + e][jl]);
    v1[e] = (short)f2bf(s[kg * 16 + 8 + e][jl]);
  }
  short8* dst = (short8*)(Wp + (size_t)p * NK + k0 + kg * 16);
  dst[0] = v0;
  dst[1] = v1;
}

__global__ __launch_bounds__(256) void wl_bsum(const float* __restrict__ bx,
                                               const float* __restrict__ bh,
                                               float* __restrict__ bsum) {
  int p = blockIdx.x * 256 + threadIdx.x;
  int j = (p & 3) * NH + (p >> 2);
  bsum[p] = bx[j] + bh[j];
}

__global__ __launch_bounds__(256) void wl_xall(const float* __restrict__ trains,
                                               const float* __restrict__ dec,
                                               const float* __restrict__ Win,
                                               const float* __restrict__ b_in,
                                               u16* __restrict__ xall) {
  int idx = blockIdx.x * 256 + threadIdx.x;
  int i = idx & 63;
  int b = (idx >> 6) & 255;
  int t = idx >> 14;
  float v;
  if (t < 128) v = trains[((size_t)b * 128 + t) * 64 + i];
  else         v = dec[b * 23 + (t - 128)] * Win[i] + b_in[i];
  xall[idx] = f2bf(v);
}

// ---- one step. 256 blocks x 256 threads (4 waves). Tile 128 x 64.
// Block mapping: cs = (bid&7)*16 + ((bid>>3)&15) in [0,128), rh = bid>>7.
// bid and bid+128 share cs and (round-robin) an XCD -> B L2-dedupe in-step.
__global__ __launch_bounds__(256) void wl_step(const u16* __restrict__ Wpg,
                                               const float* __restrict__ bsum,
                                               const u16* __restrict__ xall,
                                               u16* __restrict__ hcat,  // 2 bufs
                                               float* __restrict__ c_t, // [u][b]
                                               float* __restrict__ ypart,
                                               const float* __restrict__ Wout,
                                               int t) {
  __shared__ char arena[73728];  // 3 bufs x (A 16K | B 8K); epilogue gtile 32KB

  const int bid = blockIdx.x;
  const int cs = (bid & 7) * 16 + ((bid >> 3) & 15);  // col-slice 0..127
  const int rh = bid >> 7;                            // row half 0/1
  const int p0 = cs * 64, u0 = cs * 16, b0 = rh * 128;

  const int tid = threadIdx.x;
  const int wv = tid >> 6, lane = tid & 63;
  const int l15 = lane & 15, lhi = lane >> 4;
  const int srow = lane >> 3, sc = lane & 7;  // staging: 8 rows x 8 chunks per KB

  const u16* __restrict__ hin = hcat + (size_t)(t & 1) * NB * NH;
  u16* __restrict__ hout = hcat + (size_t)((t + 1) & 1) * NB * NH;

  f32x4 acc[2][4] = {};

  // stage tile kt into buf: A 128x64 (16KB, self-rows per wave) + B 64x64 (8KB)
  auto stage = [&](int kt, int buf) {
    char* const base = arena + buf * 24576;
    const u16* asrc; size_t astr;
    if (kt < 32) { asrc = hin + (size_t)b0 * NH + (size_t)kt * 64; astr = NH; }
    else         { asrc = xall + ((size_t)t * NB + b0) * NI;       astr = NI; }
#pragma unroll
    for (int i = 0; i < 4; ++i) {
      int qa = wv * 4 + i;                 // 1KB chunk 0..15
      int row = qa * 8 + srow;             // 0..127 (this wave's own rows)
      int g8 = sc ^ (row & 7);
      gload16(asrc + (size_t)row * astr + g8 * 8, base + qa * 1024);
    }
    const u16* bsrc = Wpg + (size_t)p0 * NK + (size_t)kt * 64;
#pragma unroll
    for (int i = 0; i < 2; ++i) {
      int qb = wv * 2 + i;                 // 0..7
      int col = qb * 8 + srow;             // 0..63
      int g8 = sc ^ (col & 7);
      gload16(bsrc + (size_t)col * NK + g8 * 8, base + 16384 + qb * 1024);
    }
  };

  auto compute = [&](int kt) {
    const char* Ab = arena + (kt % 3) * 24576;
    const char* Bb = Ab + 16384;
#pragma unroll
    for (int kc = 0; kc < 2; ++kc) {
      const int c8 = kc * 4 + lhi;
      bf16x8 bfr[4];
#pragma unroll
      for (int n = 0; n < 4; ++n) {
        int col = n * 16 + l15;
        bfr[n] = *(const bf16x8*)(Bb + col * 128 + ((c8 ^ (col & 7)) << 4));
      }
#pragma unroll
      for (int m = 0; m < 2; ++m) {
        int row = wv * 32 + m * 16 + l15;
        bf16x8 afr = *(const bf16x8*)(Ab + row * 128 + ((c8 ^ (row & 7)) << 4));
#pragma unroll
        for (int n = 0; n < 4; ++n)
          acc[m][n] = __builtin_amdgcn_mfma_f32_16x16x32_bf16(afr, bfr[n], acc[m][n], 0, 0, 0);
      }
    }
  };

  stage(0, 0); stage(1, 1); stage(2, 2);   // 18 issues/wave in flight
  for (int kt = 0; kt < 33; ++kt) {
    // outstanding tiles: kt .. min(32, kt+2); wait until tile kt's 6 complete
    if (kt < 31)       asm volatile("s_waitcnt vmcnt(12)" ::: "memory");
    else if (kt == 31) asm volatile("s_waitcnt vmcnt(6)" ::: "memory");
    else               asm volatile("s_waitcnt vmcnt(0)" ::: "memory");
    asm volatile("s_barrier" ::: "memory");          // RAW barrier: no vmcnt(0) drain
    compute(kt);
    asm volatile("s_barrier" ::: "memory");          // buf consumed by all waves
    if (kt + 3 < 33) stage(kt + 3, kt % 3);          // refill freed buf
  }

  // ---- spill acc -> gtile [col 0..63][chunk 0..31 (=row>>2)] swizzled, 32KB
  asm volatile("s_barrier" ::: "memory");
#pragma unroll
  for (int m = 0; m < 2; ++m)
#pragma unroll
    for (int n = 0; n < 4; ++n) {
      int col = n * 16 + l15;
      int chunk = wv * 8 + m * 4 + lhi;    // row>>2
      *(f32x4*)(arena + col * 512 + ((chunk ^ (col & 7)) << 4)) = acc[m][n];
    }
  __syncthreads();

  // ---- gates + state: thread -> (row bl, unit-group ug of 8 units)
  {
    const int bl = tid & 127, ug = tid >> 7;
    const int bg = b0 + bl;
    const bool emit = (t >= 127);
    float yacc = 0.f;
    short8 hv;
#pragma unroll
    for (int j = 0; j < 8; ++j) {
      int ul = ug * 8 + j;                 // local unit 0..15
      float g[4];
#pragma unroll
      for (int gi = 0; gi < 4; ++gi) {
        int col = ul * 4 + gi;
        g[gi] = *(const float*)(arena + col * 512 +
                                (((bl >> 2) ^ (col & 7)) << 4) + (bl & 3) * 4);
      }
      const float4 bs = *(const float4*)(bsum + p0 + ul * 4);
      float si = sigmoidf_(g[0] + bs.x);
      float sf = sigmoidf_(g[1] + bs.y);
      float so = sigmoidf_(g[2] + bs.z);
      float tc = tanhf_(g[3] + bs.w);
      size_t ci = (size_t)(u0 + ul) * NB + bg;
      float cn = sf * c_t[ci] + si * tc;
      float h = so * tanhf_(cn);
      c_t[ci] = cn;
      hv[j] = (short)f2bf(h);
      if (emit) yacc += h * Wout[u0 + ul];
    }
    *(short8*)(hout + (size_t)bg * NH + u0 + ug * 8) = hv;  // 16B store
    if (emit) ypart[((size_t)(t - 127) * 256 + cs * 2 + ug) * NB + bg] = yacc;
  }
}

// ---- y[b][j] = bout + sum_{s<256} ypart[j][s][b]
__global__ __launch_bounds__(256) void wl_finy(const float* __restrict__ ypart,
                                               const float* __restrict__ bout,
                                               float* __restrict__ out) {
  int j = blockIdx.x;
  int b = threadIdx.x;
  const float* yp = ypart + (size_t)j * 256 * NB;
  float s = bout[0];
#pragma unroll 8
  for (int i = 0; i < 256; ++i) s += yp[i * NB + b];
  out[b * NO + j] = s;
}

extern "C" void kernel_launch(void* const* d_in, const int* in_sizes, int n_in,
                              void* d_out, int out_size, void* d_ws, size_t ws_size,
                              hipStream_t stream) {
  const float* trains = (const float*)d_in[0];
  const float* dec    = (const float*)d_in[1];
  const float* Wx     = (const float*)d_in[2];
  const float* bx     = (const float*)d_in[3];
  const float* Wh     = (const float*)d_in[4];
  const float* bh     = (const float*)d_in[5];
  const float* Win    = (const float*)d_in[6];
  const float* b_in   = (const float*)d_in[7];
  const float* Wout   = (const float*)d_in[8];
  const float* bout   = (const float*)d_in[9];
  float* out = (float*)d_out;
  char* ws = (char*)d_ws;

  u16*   Wp    = (u16*)(ws);                  // 34,603,008
  float* bsum  = (float*)(ws + 34603008);     //     32,768
  u16*   xall  = (u16*)(ws + 34635776);       //  4,947,968 -> 39,583,744
  u16*   hcat  = (u16*)(ws + 39583744);       //  2,097,152 -> 41,680,896
  float* c_t   = (float*)(ws + 41680896);     //  2,097,152 -> 43,778,048
  float* ypart = (float*)(ws + 43778048);     //  6,291,456 -> 50,069,504

  // zero hcat (both bufs) + c_t in one memset
  hipMemsetAsync(ws + 39583744, 0, 4194304, stream);
  wl_pack_w<<<dim3(128, 33), 256, 0, stream>>>(Wx, Wh, Wp);
  wl_bsum<<<32, 256, 0, stream>>>(bx, bh, bsum);
  wl_xall<<<(NSTEPS * NB * NI) / 256, 256, 0, stream>>>(trains, dec, Win, b_in, xall);
  for (int t = 0; t < NSTEPS; ++t)
    wl_step<<<256, 256, 0, stream>>>(Wp, bsum, xall, hcat, c_t, ypart, Wout, t);
  wl_finy<<<NO, 256, 0, stream>>>(ypart, bout, out);
}

// Round 7
// 2961.383 us; speedup vs baseline: 3.4411x; 1.0447x over previous
//
#include <hip/hip_runtime.h>

// WeatherLSTM: B=256, T=128, I=64, H=2048, O=24
// R6b: per-step kernels, tile 128 rows x 64 packed cols (128 slices x 2 halves,
// XCD-paired). Depth-5 pipeline over 6 LDS buffers, ONE raw s_barrier per
// k-iter, counted vmcnt. 512 threads (8 waves). Wp read once/step from L3.
// (R6 retry: 'short4' typedef collided with HIP's built-in short4.)

#define NB 256
#define NH 2048
#define NI 64
#define NK 2112
#define NPK 8192
#define NSTEPS 151
#define NO 24

typedef __bf16 bf16x8 __attribute__((ext_vector_type(8)));
typedef short short8 __attribute__((ext_vector_type(8)));
typedef short s16x4 __attribute__((ext_vector_type(4)));
typedef float f32x4 __attribute__((ext_vector_type(4)));
typedef unsigned short u16;

__device__ __forceinline__ u16 f2bf(float f) {
  union { float f; unsigned u; } v; v.f = f;
  unsigned r = v.u + 0x7FFFu + ((v.u >> 16) & 1u);  // RNE
  return (u16)(r >> 16);
}

__device__ __forceinline__ void gload16(const void* g, void* l) {
  __builtin_amdgcn_global_load_lds(
      (const __attribute__((address_space(1))) unsigned int*)g,
      (__attribute__((address_space(3))) unsigned int*)l, 16, 0, 0);
}

__device__ __forceinline__ float sigmoidf_(float x) { return 1.f / (1.f + __expf(-x)); }
__device__ __forceinline__ float tanhf_(float x) {
  x = fminf(15.f, fmaxf(-15.f, x));
  float e = __expf(2.f * x);
  return (e - 1.f) / (e + 1.f);
}

// ---- pack [Wh;Wx] fp32 [k][4H] -> Wp bf16 [p][k], p = u*4+g
__global__ __launch_bounds__(256) void wl_pack_w(const float* __restrict__ Wx,
                                                 const float* __restrict__ Wh,
                                                 u16* __restrict__ Wp) {
  __shared__ float s[64][65];
  const int j0 = blockIdx.x * 64, k0 = blockIdx.y * 64;
  const int tid = threadIdx.x;
  const int jl = tid & 63, kg = tid >> 6;
#pragma unroll
  for (int it = 0; it < 16; ++it) {
    int kl = it * 4 + kg;
    int k = k0 + kl, j = j0 + jl;
    float v = (k < NH) ? Wh[(size_t)k * NPK + j] : Wx[(size_t)(k - NH) * NPK + j];
    s[kl][jl] = v;
  }
  __syncthreads();
  int j = j0 + jl;
  int p = (j & (NH - 1)) * 4 + (j >> 11);
  short8 v0, v1;
#pragma unroll
  for (int e = 0; e < 8; ++e) {
    v0[e] = (short)f2bf(s[kg * 16 + e][jl]);
    v1[e] = (short)f2bf(s[kg * 16 + 8 + e][jl]);
  }
  short8* dst = (short8*)(Wp + (size_t)p * NK + k0 + kg * 16);
  dst[0] = v0;
  dst[1] = v1;
}

__global__ __launch_bounds__(256) void wl_bsum(const float* __restrict__ bx,
                                               const float* __restrict__ bh,
                                               float* __restrict__ bsum) {
  int p = blockIdx.x * 256 + threadIdx.x;
  int j = (p & 3) * NH + (p >> 2);
  bsum[p] = bx[j] + bh[j];
}

__global__ __launch_bounds__(256) void wl_xall(const float* __restrict__ trains,
                                               const float* __restrict__ dec,
                                               const float* __restrict__ Win,
                                               const float* __restrict__ b_in,
                                               u16* __restrict__ xall) {
  int idx = blockIdx.x * 256 + threadIdx.x;
  int i = idx & 63;
  int b = (idx >> 6) & 255;
  int t = idx >> 14;
  float v;
  if (t < 128) v = trains[((size_t)b * 128 + t) * 64 + i];
  else         v = dec[b * 23 + (t - 128)] * Win[i] + b_in[i];
  xall[idx] = f2bf(v);
}

// ---- one step. 256 blocks x 512 threads (8 waves). Tile 128 x 64.
// cs = (bid&7)*16 + ((bid>>3)&15), rh = bid>>7; bid and bid+128 share cs and
// an XCD (128%8==0) -> B L2-dedupe in-step.
__global__ __launch_bounds__(512) void wl_step(const u16* __restrict__ Wpg,
                                               const float* __restrict__ bsum,
                                               const u16* __restrict__ xall,
                                               u16* __restrict__ hcat,  // 2 bufs
                                               float* __restrict__ c_t, // [u][b]
                                               float* __restrict__ ypart,
                                               const float* __restrict__ Wout,
                                               int t) {
  __shared__ char arena[147456];  // 6 bufs x (A 16K | B 8K); epilogue gtile 32KB

  const int bid = blockIdx.x;
  const int cs = (bid & 7) * 16 + ((bid >> 3) & 15);  // col-slice 0..127
  const int rh = bid >> 7;                            // row half 0/1
  const int p0 = cs * 64, u0 = cs * 16, b0 = rh * 128;

  const int tid = threadIdx.x;
  const int wv = tid >> 6, lane = tid & 63;           // wv 0..7
  const int l15 = lane & 15, lhi = lane >> 4;
  const int srow = lane >> 3, sc = lane & 7;          // staging: 8 rows x 8 chunks/KB
  const int g8 = sc ^ srow;                           // pre-swizzled chunk (row&7==srow)

  const u16* __restrict__ hin = hcat + (size_t)(t & 1) * NB * NH;
  u16* __restrict__ hout = hcat + (size_t)((t + 1) & 1) * NB * NH;

  f32x4 acc[4] = {};

  // stage tile kt into buf: A 128x64 (16KB) + B 64x64 (8KB); 3 loads/wave
  auto stage = [&](int kt, int buf) {
    char* const base = arena + buf * 24576;
    const u16* asrc; size_t astr;
    if (kt < 32) { asrc = hin + (size_t)b0 * NH + (size_t)kt * 64; astr = NH; }
    else         { asrc = xall + ((size_t)t * NB + b0) * NI;       astr = NI; }
#pragma unroll
    for (int i = 0; i < 2; ++i) {
      int qa = wv * 2 + i;                 // 1KB chunk 0..15
      int row = qa * 8 + srow;             // 0..127
      gload16(asrc + (size_t)row * astr + g8 * 8, base + qa * 1024);
    }
    const u16* bsrc = Wpg + (size_t)p0 * NK + (size_t)kt * 64;
    {
      int col = wv * 8 + srow;             // 0..63
      gload16(bsrc + (size_t)col * NK + g8 * 8, base + 16384 + wv * 1024);
    }
  };

  auto compute = [&](int kt, int buf) {
    const char* Ab = arena + buf * 24576;
    const char* Bb = Ab + 16384;
#pragma unroll
    for (int kc = 0; kc < 2; ++kc) {
      const int c8 = kc * 4 + lhi;
      bf16x8 bfr[4];
#pragma unroll
      for (int n = 0; n < 4; ++n) {
        int col = n * 16 + l15;
        bfr[n] = *(const bf16x8*)(Bb + col * 128 + ((c8 ^ (col & 7)) << 4));
      }
      int row = wv * 16 + l15;
      bf16x8 afr = *(const bf16x8*)(Ab + row * 128 + ((c8 ^ (row & 7)) << 4));
#pragma unroll
      for (int n = 0; n < 4; ++n)
        acc[n] = __builtin_amdgcn_mfma_f32_16x16x32_bf16(afr, bfr[n], acc[n], 0, 0, 0);
    }
  };

  // prologue: 5 tiles in flight (15 loads/wave)
  stage(0, 0); stage(1, 1); stage(2, 2); stage(3, 3); stage(4, 4);
  int buf = 0;
  for (int kt = 0; kt < 33; ++kt) {
    // wait until tile kt's 3 loads (this wave) complete
    if (kt < 29)       asm volatile("s_waitcnt vmcnt(12)" ::: "memory");
    else if (kt == 29) asm volatile("s_waitcnt vmcnt(9)" ::: "memory");
    else if (kt == 30) asm volatile("s_waitcnt vmcnt(6)" ::: "memory");
    else if (kt == 31) asm volatile("s_waitcnt vmcnt(3)" ::: "memory");
    else               asm volatile("s_waitcnt vmcnt(0)" ::: "memory");
    asm volatile("s_barrier" ::: "memory");  // all waves: tile kt resident; AND
                                             // all waves finished compute(kt-1)
    if (kt <= 27) {
      int sb = buf + 5; if (sb >= 6) sb -= 6;
      stage(kt + 5, sb);                     // overwrites buf read at kt-1: safe
    }
    compute(kt, buf);
    if (++buf == 6) buf = 0;
  }

  // ---- spill acc -> gtile [col 0..63][chunk(row>>2) 0..31] swizzled, 32KB
  __syncthreads();  // vmcnt already 0; ensures all waves past compute(32)
#pragma unroll
  for (int n = 0; n < 4; ++n) {
    int col = n * 16 + l15;
    int chunk = wv * 4 + lhi;              // row>>2, row = wv*16 + lhi*4
    *(f32x4*)(arena + col * 512 + ((chunk ^ (col & 7)) << 4)) = acc[n];
  }
  __syncthreads();

  // ---- gates + state: thread -> (row bl, unit-group ug of 4 units)
  {
    const int bl = tid & 127, ug = tid >> 7;  // ug 0..3
    const int bg = b0 + bl;
    const bool emit = (t >= 127);
    float yacc = 0.f;
    s16x4 hv;
#pragma unroll
    for (int j = 0; j < 4; ++j) {
      int ul = ug * 4 + j;                 // local unit 0..15
      float g[4];
#pragma unroll
      for (int gi = 0; gi < 4; ++gi) {
        int col = ul * 4 + gi;
        g[gi] = *(const float*)(arena + col * 512 +
                                (((bl >> 2) ^ (col & 7)) << 4) + (bl & 3) * 4);
      }
      const float4 bs = *(const float4*)(bsum + p0 + ul * 4);
      float si = sigmoidf_(g[0] + bs.x);
      float sf = sigmoidf_(g[1] + bs.y);
      float so = sigmoidf_(g[2] + bs.z);
      float tc = tanhf_(g[3] + bs.w);
      size_t ci = (size_t)(u0 + ul) * NB + bg;
      float cn = sf * c_t[ci] + si * tc;
      float h = so * tanhf_(cn);
      c_t[ci] = cn;
      hv[j] = (short)f2bf(h);
      if (emit) yacc += h * Wout[u0 + ul];
    }
    *(s16x4*)(hout + (size_t)bg * NH + u0 + ug * 4) = hv;  // 8B store
    if (emit) ypart[((size_t)(t - 127) * 512 + cs * 4 + ug) * NB + bg] = yacc;
  }
}

// ---- y[b][j] = bout + sum_{s<512} ypart[j][s][b]
__global__ __launch_bounds__(256) void wl_finy(const float* __restrict__ ypart,
                                               const float* __restrict__ bout,
                                               float* __restrict__ out) {
  int j = blockIdx.x;
  int b = threadIdx.x;
  const float* yp = ypart + (size_t)j * 512 * NB;
  float s = bout[0];
#pragma unroll 8
  for (int i = 0; i < 512; ++i) s += yp[i * NB + b];
  out[b * NO + j] = s;
}

extern "C" void kernel_launch(void* const* d_in, const int* in_sizes, int n_in,
                              void* d_out, int out_size, void* d_ws, size_t ws_size,
                              hipStream_t stream) {
  const float* trains = (const float*)d_in[0];
  const float* dec    = (const float*)d_in[1];
  const float* Wx     = (const float*)d_in[2];
  const float* bx     = (const float*)d_in[3];
  const float* Wh     = (const float*)d_in[4];
  const float* bh     = (const float*)d_in[5];
  const float* Win    = (const float*)d_in[6];
  const float* b_in   = (const float*)d_in[7];
  const float* Wout   = (const float*)d_in[8];
  const float* bout   = (const float*)d_in[9];
  float* out = (float*)d_out;
  char* ws = (char*)d_ws;

  u16*   Wp    = (u16*)(ws);                  // 34,603,008
  float* bsum  = (float*)(ws + 34603008);     //     32,768
  u16*   xall  = (u16*)(ws + 34635776);       //  4,947,968 -> 39,583,744
  u16*   hcat  = (u16*)(ws + 39583744);       //  2,097,152 -> 41,680,896
  float* c_t   = (float*)(ws + 41680896);     //  2,097,152 -> 43,778,048
  float* ypart = (float*)(ws + 43778048);     // 12,582,912 -> 56,360,960

  // zero hcat (both bufs) + c_t in one memset
  (void)hipMemsetAsync(ws + 39583744, 0, 4194304, stream);
  wl_pack_w<<<dim3(128, 33), 256, 0, stream>>>(Wx, Wh, Wp);
  wl_bsum<<<32, 256, 0, stream>>>(bx, bh, bsum);
  wl_xall<<<(NSTEPS * NB * NI) / 256, 256, 0, stream>>>(trains, dec, Win, b_in, xall);
  for (int t = 0; t < NSTEPS; ++t)
    wl_step<<<256, 512, 0, stream>>>(Wp, bsum, xall, hcat, c_t, ypart, Wout, t);
  wl_finy<<<NO, 256, 0, stream>>>(ypart, bout, out);
}